// Round 1
// baseline (99.384 us; speedup 1.0000x reference)
//
#include <hip/hip_runtime.h>

// SlotContrastiveLoss: B=32768, K=8, D=256 fp32.
// One wave64 per batch: float4/lane row fragments, register butterfly
// reduce-scatter delivers logits[k][j] to lane k*8+j, shfl-group LSE,
// deterministic two-stage final reduction (no float atomics).

#define GSTAGE(P, NH) do {                                              \
    const unsigned bp = (lane >> (P)) & 1u;                             \
    _Pragma("unroll")                                                   \
    for (int c = 0; c < (NH); ++c) {                                    \
      float keep = bp ? g[(NH) + c] : g[c];                             \
      float send = bp ? g[c] : g[(NH) + c];                             \
      g[c] = keep + __shfl_xor(send, 1 << (P), 64);                     \
    }                                                                   \
  } while (0)

#define NSTAGE(arr, LB, NH, MASK) do {                                  \
    const unsigned bp = (lane >> (LB)) & 1u;                            \
    _Pragma("unroll")                                                   \
    for (int c = 0; c < (NH); ++c) {                                    \
      float keep = bp ? arr[(NH) + c] : arr[c];                         \
      float send = bp ? arr[c] : arr[(NH) + c];                         \
      arr[c] = keep + __shfl_xor(send, (MASK), 64);                     \
    }                                                                   \
  } while (0)

extern "C" __global__ __launch_bounds__(256, 2)
void slot_ce_main(const float* __restrict__ ds, const float* __restrict__ ss,
                  const float* __restrict__ tptr, float* __restrict__ ws,
                  int B, int nwaves) {
  const int tid  = blockIdx.x * blockDim.x + threadIdx.x;
  const int wave = tid >> 6;
  const int lane = threadIdx.x & 63;
  const float inv_t = 1.0f / tptr[0];

  float acc = 0.0f;

  for (int b = wave; b < B; b += nwaves) {
    const float4* av = (const float4*)(ds + (size_t)b * 2048);
    const float4* sv = (const float4*)(ss + (size_t)b * 2048);
    float4 A[8], S[8];
#pragma unroll
    for (int k = 0; k < 8; ++k) {
      A[k] = av[k * 64 + lane];   // row k, bytes 16*lane..: coalesced 1KB/instr
      S[k] = sv[k * 64 + lane];
    }

    // per-lane partial dots: g[k*8+j] = <A_k, S_j> over this lane's 4 elems
    float g[64];
#pragma unroll
    for (int k = 0; k < 8; ++k)
#pragma unroll
      for (int j = 0; j < 8; ++j)
        g[k * 8 + j] = A[k].x * S[j].x + A[k].y * S[j].y +
                       A[k].z * S[j].z + A[k].w * S[j].w;

    float na[8], nb[8];
#pragma unroll
    for (int k = 0; k < 8; ++k) {
      na[k] = A[k].x * A[k].x + A[k].y * A[k].y + A[k].z * A[k].z + A[k].w * A[k].w;
      nb[k] = S[k].x * S[k].x + S[k].y * S[k].y + S[k].z * S[k].z + S[k].w * S[k].w;
    }

    // butterfly reduce-scatter: lane l ends with full G for index l (k=l>>3, j=l&7)
    GSTAGE(5, 32); GSTAGE(4, 16); GSTAGE(3, 8);
    GSTAGE(2, 4);  GSTAGE(1, 2);  GSTAGE(0, 1);

    // na -> lane gets na[lane>>3]; distribute bits 5,4,3 then fold 2,1,0
    NSTAGE(na, 5, 4, 32); NSTAGE(na, 4, 2, 16); NSTAGE(na, 3, 1, 8);
    na[0] += __shfl_xor(na[0], 4, 64);
    na[0] += __shfl_xor(na[0], 2, 64);
    na[0] += __shfl_xor(na[0], 1, 64);
    // nb -> lane gets nb[lane&7]; distribute bits 2,1,0 then fold 5,4,3
    NSTAGE(nb, 2, 4, 4); NSTAGE(nb, 1, 2, 2); NSTAGE(nb, 0, 1, 1);
    nb[0] += __shfl_xor(nb[0], 32, 64);
    nb[0] += __shfl_xor(nb[0], 16, 64);
    nb[0] += __shfl_xor(nb[0],  8, 64);

    // logits[k][j] at lane l; norms ~16 so eps=1e-12 branch is dead
    float logit = g[0] * rsqrtf(na[0] * nb[0]) * inv_t;

    // logsumexp over j (lanes sharing bits 5..3)
    float m = logit;
    m = fmaxf(m, __shfl_xor(m, 1, 64));
    m = fmaxf(m, __shfl_xor(m, 2, 64));
    m = fmaxf(m, __shfl_xor(m, 4, 64));
    float e = __expf(logit - m);
    e += __shfl_xor(e, 1, 64);
    e += __shfl_xor(e, 2, 64);
    e += __shfl_xor(e, 4, 64);
    float lse = m + __logf(e);

    acc += lse * 0.125f;                       // replicated 8x per k -> /8
    if ((lane >> 3) == (lane & 7)) acc -= logit;  // diagonal
  }

  // deterministic block reduction
  __shared__ float red[4];
#pragma unroll
  for (int o = 32; o >= 1; o >>= 1) acc += __shfl_xor(acc, o, 64);
  if (lane == 0) red[threadIdx.x >> 6] = acc;
  __syncthreads();
  if (threadIdx.x == 0)
    ws[blockIdx.x] = (red[0] + red[1]) + (red[2] + red[3]);
}

extern "C" __global__ __launch_bounds__(256)
void slot_ce_finish(const float* __restrict__ ws, float* __restrict__ out,
                    int nparts, float scale) {
  __shared__ float red[256];
  float s = 0.0f;
  for (int i = threadIdx.x; i < nparts; i += 256) s += ws[i];
  red[threadIdx.x] = s;
  __syncthreads();
  for (int o = 128; o >= 1; o >>= 1) {
    if ((int)threadIdx.x < o) red[threadIdx.x] += red[threadIdx.x + o];
    __syncthreads();
  }
  if (threadIdx.x == 0) out[0] = red[0] * scale;
}

extern "C" void kernel_launch(void* const* d_in, const int* in_sizes, int n_in,
                              void* d_out, int out_size, void* d_ws, size_t ws_size,
                              hipStream_t stream) {
  const float* ds   = (const float*)d_in[0];
  const float* ss   = (const float*)d_in[1];
  const float* tptr = (const float*)d_in[3];   // d_in[2] = labels (unused)
  float* out = (float*)d_out;
  float* ws  = (float*)d_ws;

  const int B = in_sizes[0] / (8 * 256);       // 32768
  const int blocks = 2048;                     // 8KB of d_ws partials
  const int nwaves = blocks * (256 / 64);

  slot_ce_main<<<blocks, 256, 0, stream>>>(ds, ss, tptr, ws, B, nwaves);
  const float scale = 1.0f / (8.0f * (float)B);
  slot_ce_finish<<<1, 256, 0, stream>>>(ws, out, blocks, scale);
}